// Round 3
// baseline (3681.258 us; speedup 1.0000x reference)
//
#include <hip/hip_runtime.h>

// LIF benchmark: xs = einsum('tbf,gf->tbg', S, W)  (fp32 GEMM, A=S [T*B,512], B=W [512,512], NT)
// then sequential scan over T with per-neuron (v,i) state and heaviside threshold.
// Outputs: [z_final, z_final, v_final, i_final], each [128,512] fp32.
//
// R8 (session R3): GEMM was LDS-read-pipe bound (per k per CU: 6 b128 reads x
// 8 waves x 12cy = 576cy + ~72 staging > 512cy VALU; predicted VALUBusy 79%,
// measured 74.5%). Fix: B leaves LDS entirely.
//   - One-time transpose kernel Wt[k][n] = W[n][k] (pure copy -> bit-exact;
//     1MB, ~2us). Compute loop loads B straight from global: Wt row k is
//     contiguous, L2-resident per XCD (1MB), coalesced across lanes.
//     Register double-buffer (static even/odd float4[4] slots) prefetches row
//     k+1 during k's 128 FMAs (256+ issue-cy covers ~300cy L2 latency).
//   - LDS keeps A only (2 b128 reads/k -> LDS ~290cy/k/CU, VALU 512cy is now
//     the binding pipe). A staging/barrier structure verbatim R7 (proven),
//     LDS 50KB -> 16.9KB.
//   - FMA order/operands identical (ascending k, same i/j order, b values
//     bitwise equal to W[n][k]) -> absmax 0.0 preserved.
// Scan: DEPTH 32 -> 64 (outstanding-loads-limited at 1.3TB/s with 4 waves/CU;
// 2x ring depth ~2x BW; 1024%64==0 keeps the fast path). Math unchanged.
// Launcher: Wt allocated in workspace between vi and xs; Tc shrinks only if
// workspace is tight (chunk logic proven in R5/R7).

#define T_DIM 1024
#define B_DIM 128
#define F_DIM 512
#define NB (B_DIM * F_DIM)  // 65536 neurons

// ---------------- W transpose: Wt[k][n] = W[n][k] ----------------
__global__ __launch_bounds__(256)
void transpose_kernel(const float* __restrict__ W, float* __restrict__ Wt) {
    __shared__ float t[64][65];
    const int bx = blockIdx.x, by = blockIdx.y;
    const int c = threadIdx.x & 63;
    const int r0 = (threadIdx.x >> 6) * 16;
    #pragma unroll
    for (int i = 0; i < 16; ++i) {
        const int row = r0 + i;
        t[row][c] = W[(size_t)(by * 64 + row) * F_DIM + bx * 64 + c];
    }
    __syncthreads();
    #pragma unroll
    for (int i = 0; i < 16; ++i) {
        const int row = r0 + i;
        Wt[(size_t)(bx * 64 + row) * F_DIM + by * 64 + c] = t[c][row];
    }
}

// ---------------- GEMM: C[m][n] = sum_k A[m][k] * Wt[k][n] ----------------
// Block tile 128m x 256n, 256 threads, 8x16 micro-tile, KC=16.
// A double-buffered in LDS; B register-double-buffered from global (Wt).
#define TM 128
#define TN 256
#define KC 16
#define LDA_S 132            // As row pad (conflict-free reads/writes)
#define A_SZ (KC * LDA_S)    // 2112 floats per buffer

__global__ __launch_bounds__(256, 2)
void gemm_kernel(const float* __restrict__ A, const float* __restrict__ Wt,
                 float* __restrict__ C) {
    __shared__ float As[2 * A_SZ];  // [buf][k][m]
    const int tid = threadIdx.x;
    const int m0 = blockIdx.x * TM;
    const int n0 = blockIdx.y * TN;
    const int tn4 = (tid & 15) * 4;  // b cols: tn4 + {0..3} + 64q, q=0..3
    const int tm4 = (tid >> 4) * 4;  // a rows: tm4 + {0..3} and +64
    const int srow = tid >> 2;       // staging row 0..63 (+64p)
    const int sk = (tid & 3) * 4;    // staging k 0,4,8,12

    float acc[8][16];
    #pragma unroll
    for (int i = 0; i < 8; ++i)
        #pragma unroll
        for (int j = 0; j < 16; ++j) acc[i][j] = 0.f;

    const float* wp = Wt + n0 + tn4;  // + k*F_DIM + 64q

    // B register double-buffer: even/odd k slots (static indexing only)
    float4 be[4], bo[4];
    #pragma unroll
    for (int q = 0; q < 4; ++q)
        be[q] = *(const float4*)(wp + 64 * q);  // row k=0

    // ---- prologue: stage A tile k0=0 into buffer 0 ----
    {
        float4 av[2];
        #pragma unroll
        for (int p = 0; p < 2; ++p)
            av[p] = *(const float4*)(A + (size_t)(m0 + srow + 64 * p) * F_DIM + sk);
        #pragma unroll
        for (int p = 0; p < 2; ++p) {
            const int r = srow + 64 * p;
            As[(sk + 0) * LDA_S + r] = av[p].x;  As[(sk + 1) * LDA_S + r] = av[p].y;
            As[(sk + 2) * LDA_S + r] = av[p].z;  As[(sk + 3) * LDA_S + r] = av[p].w;
        }
        __syncthreads();
    }

#define COMPUTE_K(KK, BSLOT)                                                   \
    {                                                                          \
        const float4 a0 = *(const float4*)(asb + (KK) * LDA_S + tm4);          \
        const float4 a1 = *(const float4*)(asb + (KK) * LDA_S + tm4 + 64);     \
        const float a[8] = {a0.x, a0.y, a0.z, a0.w, a1.x, a1.y, a1.z, a1.w};   \
        const float b[16] = {BSLOT[0].x, BSLOT[0].y, BSLOT[0].z, BSLOT[0].w,   \
                             BSLOT[1].x, BSLOT[1].y, BSLOT[1].z, BSLOT[1].w,   \
                             BSLOT[2].x, BSLOT[2].y, BSLOT[2].z, BSLOT[2].w,   \
                             BSLOT[3].x, BSLOT[3].y, BSLOT[3].z, BSLOT[3].w};  \
        _Pragma("unroll")                                                      \
        for (int i = 0; i < 8; ++i)                                            \
            _Pragma("unroll")                                                  \
            for (int j = 0; j < 16; ++j)                                       \
                acc[i][j] += a[i] * b[j];                                      \
    }

    int cur = 0;
    for (int k0 = 0; k0 < F_DIM; k0 += KC) {
        const bool more = (k0 + KC < F_DIM);
        // issue next A-tile's global loads first (latency hides under compute)
        float4 av[2];
        if (more) {
            #pragma unroll
            for (int p = 0; p < 2; ++p)
                av[p] = *(const float4*)(A + (size_t)(m0 + srow + 64 * p) * F_DIM
                                           + (k0 + KC) + sk);
        }

        const float* asb = As + cur * A_SZ;
        #pragma unroll
        for (int kk = 0; kk < KC; kk += 2) {
            const int k = k0 + kk;
            // prefetch odd slot: row k+1 (k <= 510 -> k+1 <= 511, always valid)
            #pragma unroll
            for (int q = 0; q < 4; ++q)
                bo[q] = *(const float4*)(wp + (size_t)(k + 1) * F_DIM + 64 * q);
            COMPUTE_K(kk, be)
            // prefetch even slot: row k+2 (clamped dead load at very end)
            const int kn = (k + 2 < F_DIM) ? (k + 2) : 0;
            #pragma unroll
            for (int q = 0; q < 4; ++q)
                be[q] = *(const float4*)(wp + (size_t)kn * F_DIM + 64 * q);
            COMPUTE_K(kk + 1, bo)
        }

        // ---- stage next A tile into buf[cur^1] ----
        if (more) {
            float* asn = As + (cur ^ 1) * A_SZ;
            #pragma unroll
            for (int p = 0; p < 2; ++p) {
                const int r = srow + 64 * p;
                asn[(sk + 0) * LDA_S + r] = av[p].x;  asn[(sk + 1) * LDA_S + r] = av[p].y;
                asn[(sk + 2) * LDA_S + r] = av[p].z;  asn[(sk + 3) * LDA_S + r] = av[p].w;
            }
            __syncthreads();
            cur ^= 1;
        }
    }
#undef COMPUTE_K

    #pragma unroll
    for (int i = 0; i < 8; ++i) {
        const int m = m0 + ((i < 4) ? (tm4 + i) : (tm4 + 60 + i));  // tm4+64+(i-4)
        #pragma unroll
        for (int q = 0; q < 4; ++q) {
            const float4 c = make_float4(acc[i][4 * q + 0], acc[i][4 * q + 1],
                                         acc[i][4 * q + 2], acc[i][4 * q + 3]);
            *(float4*)(C + (size_t)m * F_DIM + n0 + tn4 + 64 * q) = c;
        }
    }
}

// ---------------- sequential LIF scan over a chunk of Tc steps ----------------
// R3/R5 structure, ring depth 32 -> 64 (more loads in flight; scan is
// outstanding-limited at 4 waves/CU). Per-step math verbatim (bit-exact).
#define DEPTH 64

__global__ __launch_bounds__(256)
void scan_kernel(const float* __restrict__ xs, float* __restrict__ vi,
                 float* __restrict__ out, int Tc, int first, int last) {
    const int j = blockIdx.x * 256 + threadIdx.x;  // neuron id, 0..NB-1
    float v, cur;
    if (first) { v = 0.f; cur = 0.f; }
    else       { v = vi[j]; cur = vi[NB + j]; }
    float z = 0.f;
    const float* pj = xs + j;

    if (Tc >= DEPTH && (Tc % DEPTH) == 0) {
        float buf[DEPTH];
        #pragma unroll
        for (int d = 0; d < DEPTH; ++d) buf[d] = pj[(size_t)d * NB];
        for (int tt = 0; tt < Tc; tt += DEPTH) {
            #pragma unroll
            for (int d = 0; d < DEPTH; ++d) {
                const float x = buf[d];
                int tn = tt + DEPTH + d;
                tn = (tn < Tc) ? tn : 0;          // clamped dead prefetch at tail
                buf[d] = pj[(size_t)tn * NB];
                const float vd = __fadd_rn(v, __fmul_rn(0.1f, __fsub_rn(cur, v)));
                const float id = __fadd_rn(cur, __fmul_rn(-0.2f, cur));
                const bool sp = vd > 1.0f;
                z = sp ? 1.f : 0.f;
                v = sp ? 0.f : vd;
                cur = __fadd_rn(id, x);
            }
        }
    } else {
        for (int t = 0; t < Tc; ++t) {
            const float x = pj[(size_t)t * NB];
            const float vd = __fadd_rn(v, __fmul_rn(0.1f, __fsub_rn(cur, v)));
            const float id = __fadd_rn(cur, __fmul_rn(-0.2f, cur));
            const bool sp = vd > 1.0f;
            z = sp ? 1.f : 0.f;
            v = sp ? 0.f : vd;
            cur = __fadd_rn(id, x);
        }
    }

    if (last) {
        out[j]           = z;
        out[NB + j]      = z;
        out[2 * NB + j]  = v;
        out[3 * NB + j]  = cur;
    } else {
        vi[j]      = v;
        vi[NB + j] = cur;
    }
}

extern "C" void kernel_launch(void* const* d_in, const int* in_sizes, int n_in,
                              void* d_out, int out_size, void* d_ws, size_t ws_size,
                              hipStream_t stream) {
    const float* S = (const float*)d_in[0];  // [T,B,F] fp32
    const float* W = (const float*)d_in[1];  // [F,F] fp32
    float* out = (float*)d_out;
    float* vi = (float*)d_ws;                  // 2*NB floats of state
    float* Wt = vi + 2 * NB;                   // 512*512 transposed W
    float* xs = Wt + (size_t)F_DIM * F_DIM;    // chunk buffer [Tc, NB]
    // pick largest power-of-two chunk Tc whose xs buffer fits the workspace
    const size_t used = (size_t)2 * NB + (size_t)F_DIM * F_DIM;
    const size_t avail_f = (ws_size / 4 > used) ? ws_size / 4 - used : 0;
    int Tc = T_DIM;
    while (Tc > 1 && (size_t)Tc * NB > avail_f) Tc >>= 1;
    const int nc = T_DIM / Tc;

    transpose_kernel<<<dim3(8, 8), 256, 0, stream>>>(W, Wt);

    for (int c = 0; c < nc; ++c) {
        const int M = Tc * B_DIM;
        dim3 grid(M / TM, F_DIM / TN);
        gemm_kernel<<<grid, 256, 0, stream>>>(S + (size_t)c * Tc * NB, Wt, xs);
        scan_kernel<<<NB / 256, 256, 0, stream>>>(xs, vi, out, Tc,
                                                  (c == 0) ? 1 : 0,
                                                  (c == nc - 1) ? 1 : 0);
    }
}

// Round 5
// 1746.843 us; speedup vs baseline: 2.1074x; 2.1074x over previous
//
#include <hip/hip_runtime.h>

// LIF benchmark: xs = einsum('tbf,gf->tbg', S, W)  (fp32 GEMM, A=S [T*B,512], B=W [512,512], NT)
// then sequential scan over T with per-neuron (v,i) state and heaviside threshold.
// Outputs: [z_final, z_final, v_final, i_final], each [128,512] fp32.
//
// R10 (session R5): RESUBMIT of R9 unchanged -- R9's bench died to a container
// acquire failure (no pytest/absmax/rocprof output), not a kernel signal.
// Audit found no OOB/hang/LDS fault mode; register budget ~300 < 512 at
// 1 wave/EU. Keeping the experiment identical so the counters answer the
// original question.
//
// R9 theory (unchanged): fix R7's structural LDS bound by GEOMETRY.
// R7 (8x16 micro): 96 LDS-B/k/thread -> per CU per k 576cy LDS > 512cy VALU.
// R9: 16x16 micro-tile, 256x256 block tile, KC=8, double-buffered LDS:
//   - bytes/FMA 0.75 -> 0.5: per CU per k = 4 waves x 8 ds_read_b128 x 12cy
//     = 384cy LDS < 512cy VALU  -> VALU is the binding pipe.
//   - acc[16][16]=256 AGPRs -> 1 wave/SIMD (1 block/CU). Fine: 256 independent
//     acc chains = full ILP in one wave; exposed cost is only the per-k0
//     staging+barrier (~150cy per 4096cy compute ~4%), global loads still
//     issue one full tile (4096cy) ahead of use.
//   - staging: lane tid owns one 8-k row strip of A and of B: 4 dwordx4
//     global + 16 ds_write_b32; write bank (4j+tid)%32 = 2-way (free, m136);
//     reads: A 16-lane broadcast + 2-way, B 2-way (free).
//   - FMA expression and ascending-k order verbatim -> absmax 0.0 preserved.
// Spill tripwire for the post-mortem: WRITE_SIZE must stay ~262144 KB.
// Scan: verbatim R3/R5/R7 (DEPTH 32, proven).

#define T_DIM 1024
#define B_DIM 128
#define F_DIM 512
#define NB (B_DIM * F_DIM)  // 65536 neurons

// ---------------- GEMM: C[m][n] = sum_k A[m][k] * W[n][k] ----------------
// Block tile 256m x 256n, 256 threads, 16x16 micro-tile, KC=8, double-buffered.
#define TM 256
#define TN 256
#define KC 8
#define LDS_ROW 260          // 256 + 4 pad (260%32==4)
#define T_SZ (KC * LDS_ROW)  // 2080 floats per buffer

__global__ __launch_bounds__(256, 1)
void gemm_kernel(const float* __restrict__ A, const float* __restrict__ W,
                 float* __restrict__ C) {
    __shared__ float As[2 * T_SZ];  // [buf][k][m]
    __shared__ float Bs[2 * T_SZ];  // [buf][k][n]
    const int tid = threadIdx.x;
    const int m0 = blockIdx.x * TM;
    const int n0 = blockIdx.y * TN;
    const int tn4 = (tid & 15) * 4;    // b cols: tn4 + {0..3} + 64q, q=0..3
    const int tmg = (tid >> 4) * 16;   // a rows: tmg + 0..15

    float acc[16][16];
    #pragma unroll
    for (int i = 0; i < 16; ++i)
        #pragma unroll
        for (int j = 0; j < 16; ++j) acc[i][j] = 0.f;

    const float* arow = A + (size_t)(m0 + tid) * F_DIM;  // lane's A row strip
    const float* brow = W + (size_t)(n0 + tid) * F_DIM;  // lane's B row strip

    // ---- prologue: stage tile k0=0 into buffer 0 ----
    {
        const float4 a0 = *(const float4*)(arow + 0);
        const float4 a1 = *(const float4*)(arow + 4);
        const float4 b0 = *(const float4*)(brow + 0);
        const float4 b1 = *(const float4*)(brow + 4);
        As[0 * LDS_ROW + tid] = a0.x;  As[1 * LDS_ROW + tid] = a0.y;
        As[2 * LDS_ROW + tid] = a0.z;  As[3 * LDS_ROW + tid] = a0.w;
        As[4 * LDS_ROW + tid] = a1.x;  As[5 * LDS_ROW + tid] = a1.y;
        As[6 * LDS_ROW + tid] = a1.z;  As[7 * LDS_ROW + tid] = a1.w;
        Bs[0 * LDS_ROW + tid] = b0.x;  Bs[1 * LDS_ROW + tid] = b0.y;
        Bs[2 * LDS_ROW + tid] = b0.z;  Bs[3 * LDS_ROW + tid] = b0.w;
        Bs[4 * LDS_ROW + tid] = b1.x;  Bs[5 * LDS_ROW + tid] = b1.y;
        Bs[6 * LDS_ROW + tid] = b1.z;  Bs[7 * LDS_ROW + tid] = b1.w;
        __syncthreads();
    }

    int cur = 0;
    for (int k0 = 0; k0 < F_DIM; k0 += KC) {
        const bool more = (k0 + KC < F_DIM);
        // issue next tile's global loads first: full-tile (4096cy) lead time
        float4 a0, a1, b0, b1;
        if (more) {
            a0 = *(const float4*)(arow + k0 + KC);
            a1 = *(const float4*)(arow + k0 + KC + 4);
            b0 = *(const float4*)(brow + k0 + KC);
            b1 = *(const float4*)(brow + k0 + KC + 4);
        }

        // ---- compute on buf[cur] ----
        const float* asb = As + cur * T_SZ;
        const float* bsb = Bs + cur * T_SZ;
        #pragma unroll
        for (int k = 0; k < KC; ++k) {
            const float4 av0 = *(const float4*)(asb + k * LDS_ROW + tmg);
            const float4 av1 = *(const float4*)(asb + k * LDS_ROW + tmg + 4);
            const float4 av2 = *(const float4*)(asb + k * LDS_ROW + tmg + 8);
            const float4 av3 = *(const float4*)(asb + k * LDS_ROW + tmg + 12);
            const float4 bv0 = *(const float4*)(bsb + k * LDS_ROW + tn4);
            const float4 bv1 = *(const float4*)(bsb + k * LDS_ROW + tn4 + 64);
            const float4 bv2 = *(const float4*)(bsb + k * LDS_ROW + tn4 + 128);
            const float4 bv3 = *(const float4*)(bsb + k * LDS_ROW + tn4 + 192);
            const float a[16] = {av0.x, av0.y, av0.z, av0.w, av1.x, av1.y, av1.z, av1.w,
                                 av2.x, av2.y, av2.z, av2.w, av3.x, av3.y, av3.z, av3.w};
            const float b[16] = {bv0.x, bv0.y, bv0.z, bv0.w, bv1.x, bv1.y, bv1.z, bv1.w,
                                 bv2.x, bv2.y, bv2.z, bv2.w, bv3.x, bv3.y, bv3.z, bv3.w};
            #pragma unroll
            for (int i = 0; i < 16; ++i)
                #pragma unroll
                for (int j = 0; j < 16; ++j)
                    acc[i][j] += a[i] * b[j];
        }

        // ---- stage next tile into buf[cur^1] ----
        if (more) {
            float* asn = As + (cur ^ 1) * T_SZ;
            float* bsn = Bs + (cur ^ 1) * T_SZ;
            asn[0 * LDS_ROW + tid] = a0.x;  asn[1 * LDS_ROW + tid] = a0.y;
            asn[2 * LDS_ROW + tid] = a0.z;  asn[3 * LDS_ROW + tid] = a0.w;
            asn[4 * LDS_ROW + tid] = a1.x;  asn[5 * LDS_ROW + tid] = a1.y;
            asn[6 * LDS_ROW + tid] = a1.z;  asn[7 * LDS_ROW + tid] = a1.w;
            bsn[0 * LDS_ROW + tid] = b0.x;  bsn[1 * LDS_ROW + tid] = b0.y;
            bsn[2 * LDS_ROW + tid] = b0.z;  bsn[3 * LDS_ROW + tid] = b0.w;
            bsn[4 * LDS_ROW + tid] = b1.x;  bsn[5 * LDS_ROW + tid] = b1.y;
            bsn[6 * LDS_ROW + tid] = b1.z;  bsn[7 * LDS_ROW + tid] = b1.w;
            __syncthreads();
            cur ^= 1;
        }
    }

    #pragma unroll
    for (int i = 0; i < 16; ++i) {
        const int m = m0 + tmg + i;
        #pragma unroll
        for (int q = 0; q < 4; ++q) {
            const float4 c = make_float4(acc[i][4 * q + 0], acc[i][4 * q + 1],
                                         acc[i][4 * q + 2], acc[i][4 * q + 3]);
            *(float4*)(C + (size_t)m * F_DIM + n0 + tn4 + 64 * q) = c;
        }
    }
}

// ---------------- sequential LIF scan over a chunk of Tc steps ----------------
// Verbatim R3/R5/R7 (passed): depth-32 register ring buffer.
// Explicit _rn intrinsics: forbid fma contraction (matches reference rounding).
#define DEPTH 32

__global__ __launch_bounds__(256)
void scan_kernel(const float* __restrict__ xs, float* __restrict__ vi,
                 float* __restrict__ out, int Tc, int first, int last) {
    const int j = blockIdx.x * 256 + threadIdx.x;  // neuron id, 0..NB-1
    float v, cur;
    if (first) { v = 0.f; cur = 0.f; }
    else       { v = vi[j]; cur = vi[NB + j]; }
    float z = 0.f;
    const float* pj = xs + j;

    if (Tc >= DEPTH && (Tc % DEPTH) == 0) {
        float buf[DEPTH];
        #pragma unroll
        for (int d = 0; d < DEPTH; ++d) buf[d] = pj[(size_t)d * NB];
        for (int tt = 0; tt < Tc; tt += DEPTH) {
            #pragma unroll
            for (int d = 0; d < DEPTH; ++d) {
                const float x = buf[d];
                int tn = tt + DEPTH + d;
                tn = (tn < Tc) ? tn : 0;          // clamped dead prefetch at tail
                buf[d] = pj[(size_t)tn * NB];
                const float vd = __fadd_rn(v, __fmul_rn(0.1f, __fsub_rn(cur, v)));
                const float id = __fadd_rn(cur, __fmul_rn(-0.2f, cur));
                const bool sp = vd > 1.0f;
                z = sp ? 1.f : 0.f;
                v = sp ? 0.f : vd;
                cur = __fadd_rn(id, x);
            }
        }
    } else {
        for (int t = 0; t < Tc; ++t) {
            const float x = pj[(size_t)t * NB];
            const float vd = __fadd_rn(v, __fmul_rn(0.1f, __fsub_rn(cur, v)));
            const float id = __fadd_rn(cur, __fmul_rn(-0.2f, cur));
            const bool sp = vd > 1.0f;
            z = sp ? 1.f : 0.f;
            v = sp ? 0.f : vd;
            cur = __fadd_rn(id, x);
        }
    }

    if (last) {
        out[j]           = z;
        out[NB + j]      = z;
        out[2 * NB + j]  = v;
        out[3 * NB + j]  = cur;
    } else {
        vi[j]      = v;
        vi[NB + j] = cur;
    }
}

extern "C" void kernel_launch(void* const* d_in, const int* in_sizes, int n_in,
                              void* d_out, int out_size, void* d_ws, size_t ws_size,
                              hipStream_t stream) {
    const float* S = (const float*)d_in[0];  // [T,B,F] fp32
    const float* W = (const float*)d_in[1];  // [F,F] fp32
    float* out = (float*)d_out;
    float* vi = (float*)d_ws;        // 2*NB floats of state
    float* xs = vi + 2 * NB;         // chunk buffer [Tc, NB]
    // pick largest power-of-two chunk Tc whose xs buffer fits the workspace
    const size_t avail_f = (ws_size / 4 > (size_t)(2 * NB)) ? ws_size / 4 - 2 * NB : 0;
    int Tc = T_DIM;
    while (Tc > 2 && (size_t)Tc * NB > avail_f) Tc >>= 1;
    const int nc = T_DIM / Tc;
    for (int c = 0; c < nc; ++c) {
        const int M = Tc * B_DIM;  // Tc>=2 -> M divisible by TM=256
        dim3 grid(M / TM, F_DIM / TN);
        gemm_kernel<<<grid, 256, 0, stream>>>(S + (size_t)c * Tc * NB, W, xs);
        scan_kernel<<<NB / 256, 256, 0, stream>>>(xs, vi, out, Tc,
                                                  (c == 0) ? 1 : 0,
                                                  (c == nc - 1) ? 1 : 0);
    }
}